// Round 11
// baseline (358.918 us; speedup 1.0000x reference)
//
#include <hip/hip_runtime.h>
#include <stdint.h>

typedef unsigned int u32;
typedef unsigned long long u64;
typedef unsigned short u16;
typedef float f32x4 __attribute__((ext_vector_type(4)));
typedef float f32x2 __attribute__((ext_vector_type(2)));
typedef short short8 __attribute__((ext_vector_type(8)));
typedef unsigned int u32x2 __attribute__((ext_vector_type(2)));
typedef unsigned int u32x4 __attribute__((ext_vector_type(4)));

#define HID  128
#define MT   16        // batch rows per WG
#define NWG  512       // 8192/16, 2 WGs per CU (guaranteed: VGPR<=128 by launch_bounds)
#define NTHR 512       // 8 waves
#define LD   136       // LDS plane stride in u16 (272B rows)

// ---- ws byte offsets ----
#define OFF_ESUM  0        // 56 u64 fixed-point error sums (x 2^20)
#define OFF_CNT   512      // 56 u32 arrival counters
#define OFF_WPACK 8192     // 644 f32: W1(256) b1(128) b2(128) b3(128) b4(2)
#define OFF_W2TH  16384    // 128x128 bf16 [n][k]
#define OFF_W3TH  49152

constexpr float CA21 = (float)(1.0/5.0);
constexpr float CA31 = (float)(3.0/40.0),   CA32 = (float)(9.0/40.0);
constexpr float CA41 = (float)(44.0/45.0),  CA42 = (float)(-56.0/15.0), CA43 = (float)(32.0/9.0);
constexpr float CA51 = (float)(19372.0/6561.0), CA52 = (float)(-25360.0/2187.0);
constexpr float CA53 = (float)(64448.0/6561.0), CA54 = (float)(-212.0/729.0);
constexpr float CA61 = (float)(9017.0/3168.0),  CA62 = (float)(-355.0/33.0);
constexpr float CA63 = (float)(46732.0/5247.0), CA64 = (float)(49.0/176.0), CA65 = (float)(-5103.0/18656.0);
constexpr float CB1 = (float)(35.0/384.0), CB3 = (float)(500.0/1113.0), CB4 = (float)(125.0/192.0);
constexpr float CB5 = (float)(-2187.0/6784.0), CB6 = (float)(11.0/84.0);
constexpr float CE1 = (float)(35.0/384.0 - 5179.0/57600.0);
constexpr float CE3 = (float)(500.0/1113.0 - 7571.0/16695.0);
constexpr float CE4 = (float)(125.0/192.0 - 393.0/640.0);
constexpr float CE5 = (float)(-2187.0/6784.0 + 92097.0/339200.0);
constexpr float CE6 = (float)(11.0/84.0 - 187.0/2100.0);
constexpr float CE7 = (float)(-1.0/40.0);

template<int N> struct IC { static constexpr int v = N; };

__device__ __forceinline__ u16 f2bf(float x) {
  u32 u = __builtin_bit_cast(u32, x);
  u32 r = (u + 0x7FFFu + ((u >> 16) & 1u)) >> 16;
  return (u16)r;
}
__device__ __forceinline__ float eluf(float x) {
  return x > 0.f ? x : (__expf(x) - 1.f);
}
// v_cvt_pk_bf16_f32: dst[15:0]=bf16(a), dst[31:16]=bf16(b) (RNE)
__device__ __forceinline__ u32 cvtpk(float a, float b) {
  u32 r; asm("v_cvt_pk_bf16_f32 %0, %1, %2" : "=v"(r) : "v"(a), "v"(b)); return r;
}

// ---------------------------------------------------------------------------
// Prologue
// ---------------------------------------------------------------------------
__global__ void prologue(const float* __restrict__ x0, const float* __restrict__ t,
                         const float* __restrict__ W1, const float* __restrict__ b1,
                         const float* __restrict__ W2, const float* __restrict__ b2,
                         const float* __restrict__ W3, const float* __restrict__ b3,
                         const float* __restrict__ W4, const float* __restrict__ b4,
                         float* __restrict__ ws, float* __restrict__ out)
{
  int gid = blockIdx.x * blockDim.x + threadIdx.x;   // 64*256 = 16384
  out[gid] = x0[gid];
  {
    int k = gid >> 7, j = gid & 127;
    u16* w2th = (u16*)((char*)ws + OFF_W2TH);
    u16* w3th = (u16*)((char*)ws + OFF_W3TH);
    w2th[j*HID + k] = f2bf(W2[gid]);
    w3th[j*HID + k] = f2bf(W3[gid]);
  }
  float* wp = ws + OFF_WPACK/4;
  if (gid < 256) wp[gid] = W1[gid];
  if (gid < 128) {
    wp[256 + gid] = b1[gid];
    wp[384 + gid] = b2[gid];
    wp[512 + gid] = b3[gid];
  }
  if (gid < 2)  wp[640 + gid] = b4[gid];
  if (gid < 256) ((u32*)ws)[gid] = 0u;   // esum64[56] + cnt[56] zeroed
}

// ---------------------------------------------------------------------------
// Persistent solver: 512 WGs x 512 threads, 2 WGs/CU.
// launch_bounds(512,4): VGPR hard-capped at 128 -> 16 waves/CU always fit ->
// co-residency (and thus spin-safety) GUARANTEED by capacity. Single-bf16
// W2/W3 (32 VGPR of fragments) keeps natural pressure ~64 so the allocator's
// preferred 64-reg tier needs no spill (r5-r7 failure mode).
// Controller: flat fixed-point u64 atomic sum (r10, deterministic).
// ---------------------------------------------------------------------------
__global__ __launch_bounds__(NTHR, 4)
void solver(const float* __restrict__ x0, const float* __restrict__ t_arr,
            const float* __restrict__ W4g, float* __restrict__ ws,
            float* __restrict__ out)
{
  const int tid  = threadIdx.x;
  const int wg   = blockIdx.x;
  const int lane = tid & 63;
  const int wv   = tid >> 6;
  const int nl   = lane & 15;      // MFMA fragment index (batch-row within tile)
  const int g    = lane >> 4;      // k-group

  __shared__ __align__(16) u16 Ahi[2][MT][LD];
  __shared__ __align__(16) float Wsm[644];
  __shared__ __align__(16) float kS[7][MT][2];
  __shared__ __align__(16) float yL[MT][2];
  __shared__ __align__(16) float y5L[MT][2];
  __shared__ __align__(16) float pD[8][MT][2];
  __shared__ u32 bcF;
  __shared__ float bcH;

  // ---- one-time setup ----
  {
    const float* wp = ws + OFF_WPACK/4;
    Wsm[tid] = wp[tid];
    if (tid < 132) Wsm[512 + tid] = wp[512 + tid];
  }
  if (tid < 32) yL[tid >> 1][tid & 1] = x0[wg*32 + tid];

  // resident W2/W3 fragments, single bf16 (A-operand: row n = wv*16+nl)
  const u16* w2th = (const u16*)((const char*)ws + OFF_W2TH);
  const u16* w3th = (const u16*)((const char*)ws + OFF_W3TH);
  short8 W2H[4], W3H[4];
  {
    const int nglob = wv*16 + nl;
#pragma unroll
    for (int ks = 0; ks < 4; ++ks) {
      int off = nglob*HID + ks*32 + g*8;
      W2H[ks] = *(const short8*)(w2th + off);
      W3H[ks] = *(const short8*)(w3th + off);
    }
  }
  // per-lane W4 slice: w4c[r][c] = W4[wv*16+g*4+r][c]
  float w4c[4][2];
#pragma unroll
  for (int r = 0; r < 4; ++r) {
    int n = wv*16 + g*4 + r;
    w4c[r][0] = W4g[n*2 + 0];
    w4c[r][1] = W4g[n*2 + 1];
  }
  __syncthreads();
  const f32x4 bv2 = *(const f32x4*)&Wsm[384 + wv*16 + g*4];
  const f32x4 bv3 = *(const f32x4*)&Wsm[512 + wv*16 + g*4];

  u64* esum = (u64*)((char*)ws + OFF_ESUM);
  u32* cnt  = (u32*)((char*)ws + OFF_CNT);

  float h = 0.5f * (t_arr[1] - t_arr[0]);
  float heff = h;

  // ---- phase A: inline stage combine (from pD) + L1 ----
  auto phaseA = [&](auto SC, int fromPD) {
    constexpr int S = decltype(SC)::v;
    const int m  = tid >> 5;        // 16 rows
    const int jc = tid & 31;        // 32 col-chunks of 4
    float ys0, ys1;
    const float y0 = yL[m][0], y1 = yL[m][1];
    if constexpr (S == 1) {
      ys0 = y0; ys1 = y1;
    } else {
      float kp0, kp1;
      if (S == 2 && !fromPD) {
        kp0 = kS[0][m][0]; kp1 = kS[0][m][1];
      } else {
        kp0 = Wsm[640]; kp1 = Wsm[641];
#pragma unroll
        for (int w = 0; w < 8; ++w) {
          f32x2 p = *(const f32x2*)&pD[w][m][0];
          kp0 += p[0]; kp1 += p[1];
        }
        if (jc < 2) kS[S-2][m][jc] = jc ? kp1 : kp0;
      }
      if constexpr (S == 2) {
        ys0 = fmaf(heff, CA21*kp0, y0);
        ys1 = fmaf(heff, CA21*kp1, y1);
      } else if constexpr (S == 3) {
        f32x2 k1 = *(const f32x2*)&kS[0][m][0];
        ys0 = fmaf(heff, CA31*k1[0] + CA32*kp0, y0);
        ys1 = fmaf(heff, CA31*k1[1] + CA32*kp1, y1);
      } else if constexpr (S == 4) {
        f32x2 k1 = *(const f32x2*)&kS[0][m][0];
        f32x2 k2 = *(const f32x2*)&kS[1][m][0];
        ys0 = fmaf(heff, CA41*k1[0] + CA42*k2[0] + CA43*kp0, y0);
        ys1 = fmaf(heff, CA41*k1[1] + CA42*k2[1] + CA43*kp1, y1);
      } else if constexpr (S == 5) {
        f32x2 k1 = *(const f32x2*)&kS[0][m][0];
        f32x2 k2 = *(const f32x2*)&kS[1][m][0];
        f32x2 k3 = *(const f32x2*)&kS[2][m][0];
        ys0 = fmaf(heff, CA51*k1[0] + CA52*k2[0] + CA53*k3[0] + CA54*kp0, y0);
        ys1 = fmaf(heff, CA51*k1[1] + CA52*k2[1] + CA53*k3[1] + CA54*kp1, y1);
      } else if constexpr (S == 6) {
        f32x2 k1 = *(const f32x2*)&kS[0][m][0];
        f32x2 k2 = *(const f32x2*)&kS[1][m][0];
        f32x2 k3 = *(const f32x2*)&kS[2][m][0];
        f32x2 k4 = *(const f32x2*)&kS[3][m][0];
        ys0 = fmaf(heff, CA61*k1[0] + CA62*k2[0] + CA63*k3[0] + CA64*k4[0] + CA65*kp0, y0);
        ys1 = fmaf(heff, CA61*k1[1] + CA62*k2[1] + CA63*k3[1] + CA64*k4[1] + CA65*kp1, y1);
      } else {  // S == 7: y5
        f32x2 k1 = *(const f32x2*)&kS[0][m][0];
        f32x2 k3 = *(const f32x2*)&kS[2][m][0];
        f32x2 k4 = *(const f32x2*)&kS[3][m][0];
        f32x2 k5 = *(const f32x2*)&kS[4][m][0];
        ys0 = fmaf(heff, CB1*k1[0] + CB3*k3[0] + CB4*k4[0] + CB5*k5[0] + CB6*kp0, y0);
        ys1 = fmaf(heff, CB1*k1[1] + CB3*k3[1] + CB4*k4[1] + CB5*k5[1] + CB6*kp1, y1);
        if (jc < 2) y5L[m][jc] = jc ? ys1 : ys0;
      }
    }
    // L1: 4 cols per thread, single-bf16 pack
    const int j0 = jc * 4;
    f32x4 w0 = *(const f32x4*)&Wsm[j0];
    f32x4 w1 = *(const f32x4*)&Wsm[128 + j0];
    f32x4 bb = *(const f32x4*)&Wsm[256 + j0];
    float v0 = eluf(fmaf(ys1, w1[0], fmaf(ys0, w0[0], bb[0])));
    float v1 = eluf(fmaf(ys1, w1[1], fmaf(ys0, w0[1], bb[1])));
    float v2 = eluf(fmaf(ys1, w1[2], fmaf(ys0, w0[2], bb[2])));
    float v3 = eluf(fmaf(ys1, w1[3], fmaf(ys0, w0[3], bb[3])));
    u32x2 hp = {cvtpk(v0, v1), cvtpk(v2, v3)};
    *(u32x2*)&Ahi[0][m][j0] = hp;
  };

  // ---- L2: plane0 -> plane1 (1 MFMA per k-step) ----
  auto mmL2 = [&]() {
    f32x4 a0 = bv2;
    __builtin_amdgcn_s_setprio(1);
#pragma unroll
    for (int ks = 0; ks < 4; ++ks) {
      short8 bh = *(const short8*)&Ahi[0][nl][ks*32 + g*8];
      a0 = __builtin_amdgcn_mfma_f32_16x16x32_bf16(W2H[ks], bh, a0, 0, 0, 0);
    }
    __builtin_amdgcn_s_setprio(0);
    float v0 = eluf(a0[0]);
    float v1 = eluf(a0[1]);
    float v2 = eluf(a0[2]);
    float v3 = eluf(a0[3]);
    u32x2 hp = {cvtpk(v0, v1), cvtpk(v2, v3)};
    const int n0 = wv*16 + g*4;
    *(u32x2*)&Ahi[1][nl][n0] = hp;
  };

  // ---- L3 + fused L4 dot -> pD ----
  auto mmL3 = [&]() {
    f32x4 a0 = bv3;
    __builtin_amdgcn_s_setprio(1);
#pragma unroll
    for (int ks = 0; ks < 4; ++ks) {
      short8 bh = *(const short8*)&Ahi[1][nl][ks*32 + g*8];
      a0 = __builtin_amdgcn_mfma_f32_16x16x32_bf16(W3H[ks], bh, a0, 0, 0, 0);
    }
    __builtin_amdgcn_s_setprio(0);
    float v0 = eluf(a0[0]);
    float v1 = eluf(a0[1]);
    float v2 = eluf(a0[2]);
    float v3 = eluf(a0[3]);
    float p0 = v0*w4c[0][0] + v1*w4c[1][0] + v2*w4c[2][0] + v3*w4c[3][0];
    float p1 = v0*w4c[0][1] + v1*w4c[1][1] + v2*w4c[2][1] + v3*w4c[3][1];
    p0 += __shfl_xor(p0, 16); p0 += __shfl_xor(p0, 32);
    p1 += __shfl_xor(p1, 16); p1 += __shfl_xor(p1, 32);
    if (lane < 16) {
      f32x2 pp = {p0, p1};
      *(f32x2*)&pD[wv][lane][0] = pp;
    }
  };

  // ---- main adaptive loop ----
  for (int iv = 0; iv < 7; ++iv) {
    const float t1 = t_arr[iv + 1];
    float tc = t_arr[iv];
    for (int s = 0; s < 8; ++s) {
      const int step = iv*8 + s;
      float rem = t1 - tc;
      if (rem <= 1e-9f) break;          // uniform across all WGs
      heff = fminf(h, rem);

      if (iv == 0 && s == 0) {          // fresh k1 eval
        phaseA(IC<1>{}, 0); __syncthreads();
        mmL2(); __syncthreads();
        mmL3(); __syncthreads();
        phaseA(IC<2>{}, 1);
      } else {
        phaseA(IC<2>{}, 0);             // FSAL: k1 = kS[0]
      }
      __syncthreads(); mmL2(); __syncthreads(); mmL3(); __syncthreads();
      phaseA(IC<3>{}, 1); __syncthreads(); mmL2(); __syncthreads(); mmL3(); __syncthreads();
      phaseA(IC<4>{}, 1); __syncthreads(); mmL2(); __syncthreads(); mmL3(); __syncthreads();
      phaseA(IC<5>{}, 1); __syncthreads(); mmL2(); __syncthreads(); mmL3(); __syncthreads();
      phaseA(IC<6>{}, 1); __syncthreads(); mmL2(); __syncthreads(); mmL3(); __syncthreads();
      phaseA(IC<7>{}, 1); __syncthreads(); mmL2(); __syncthreads(); mmL3(); __syncthreads();
      // pD now holds k7 partials

      // ---- error partial (wave 0) + deterministic fixed-point publish ----
      if (wv == 0 && lane < 32) {
        int m = lane >> 1, c = lane & 1;
        float kp = Wsm[640 + c];
#pragma unroll
        for (int w = 0; w < 8; ++w) kp += pD[w][m][c];
        kS[6][m][c] = kp;
        float e = heff * (CE1*kS[0][m][c] + CE3*kS[2][m][c] + CE4*kS[3][m][c]
                        + CE5*kS[4][m][c] + CE6*kS[5][m][c] + CE7*kp);
        float tol = 1e-4f + 1e-3f * fmaxf(fabsf(yL[m][c]), fabsf(y5L[m][c]));
        float rr = e / tol;
        float es = rr * rr;
#pragma unroll
        for (int mk = 1; mk < 32; mk <<= 1) es += __shfl_xor(es, mk);
        if (lane == 0) {
          if (!(es < 1e8f)) es = 1e8f;          // clamp; also catches NaN
          u64 q = (u64)(es * 1048576.0f);       // x 2^20 fixed point
          __hip_atomic_fetch_add(&esum[step], q, __ATOMIC_RELAXED, __HIP_MEMORY_SCOPE_AGENT);
          __hip_atomic_fetch_add(&cnt[step], 1u, __ATOMIC_RELEASE, __HIP_MEMORY_SCOPE_AGENT);
        }
      }
      // ---- every WG: poll + local identical decision ----
      if (tid == 0) {
        while (__hip_atomic_load(&cnt[step], __ATOMIC_ACQUIRE, __HIP_MEMORY_SCOPE_AGENT) < (u32)NWG)
          __builtin_amdgcn_s_sleep(1);
        u64 q = __hip_atomic_load(&esum[step], __ATOMIC_RELAXED, __HIP_MEMORY_SCOPE_AGENT);
        float sum = (float)q * (1.0f/1048576.0f);
        float err_norm = sqrtf(sum * (1.0f/16384.f));
        bool acc = (err_norm <= 1.0f);
        float factor = fminf(10.f, fmaxf(0.2f, 0.9f * powf(fmaxf(err_norm, 1e-10f), -0.2f)));
        bcF = acc ? 1u : 0u;
        bcH = heff * factor;
      }
      __syncthreads();
      {
        bool acc = bcF != 0u;
        if (acc) {
          if (tid < 32) { int m = tid >> 1, c = tid & 1;
            yL[m][c] = y5L[m][c];
            kS[0][m][c] = kS[6][m][c];   // FSAL: k1 <- k7
          }
          tc += heff;
        }
        h = bcH;
      }
      __syncthreads();
    }
    if (tid < 32)
      out[(size_t)(iv + 1) * 16384 + wg*32 + tid] = yL[tid >> 1][tid & 1];
  }
}

extern "C" void kernel_launch(void* const* d_in, const int* in_sizes, int n_in,
                              void* d_out, int out_size, void* d_ws, size_t ws_size,
                              hipStream_t stream)
{
  const float* x0 = (const float*)d_in[0];
  const float* t  = (const float*)d_in[1];
  const float* W1 = (const float*)d_in[2];
  const float* b1 = (const float*)d_in[3];
  const float* W2 = (const float*)d_in[4];
  const float* b2 = (const float*)d_in[5];
  const float* W3 = (const float*)d_in[6];
  const float* b3 = (const float*)d_in[7];
  const float* W4 = (const float*)d_in[8];
  const float* b4 = (const float*)d_in[9];
  float* out = (float*)d_out;
  float* ws  = (float*)d_ws;

  prologue<<<64, 256, 0, stream>>>(x0, t, W1, b1, W2, b2, W3, b3, W4, b4, ws, out);
  solver<<<NWG, NTHR, 0, stream>>>(x0, t, W4, ws, out);
}

// Round 12
// 198.901 us; speedup vs baseline: 1.8045x; 1.8045x over previous
//
#include <hip/hip_runtime.h>
#include <stdint.h>

typedef unsigned int u32;
typedef unsigned long long u64;
typedef unsigned short u16;
typedef float f32x4 __attribute__((ext_vector_type(4)));
typedef float f32x2 __attribute__((ext_vector_type(2)));
typedef short short8 __attribute__((ext_vector_type(8)));
typedef unsigned int u32x2 __attribute__((ext_vector_type(2)));
typedef unsigned int u32x4 __attribute__((ext_vector_type(4)));

#define HID  128
#define MT   32        // batch rows per WG
#define NWG  256       // 8192/32, 1 WG/CU -- r11 falsified 2 WG/CU (lockstep barrier)
#define NTHR 512       // 8 waves
#define LD   136       // LDS plane stride in u16 (272B rows)

// ---- ws byte offsets ----
#define OFF_ESUM  0        // 56 u64 fixed-point error sums (x 2^20)
#define OFF_CNT   512      // 56 u32 arrival counters
#define OFF_WPACK 8192     // 644 f32: W1(256) b1(128) b2(128) b3(128) b4(2)
#define OFF_W2TH  16384    // 128x128 bf16 [n][k]
#define OFF_W3TH  49152

constexpr float CA21 = (float)(1.0/5.0);
constexpr float CA31 = (float)(3.0/40.0),   CA32 = (float)(9.0/40.0);
constexpr float CA41 = (float)(44.0/45.0),  CA42 = (float)(-56.0/15.0), CA43 = (float)(32.0/9.0);
constexpr float CA51 = (float)(19372.0/6561.0), CA52 = (float)(-25360.0/2187.0);
constexpr float CA53 = (float)(64448.0/6561.0), CA54 = (float)(-212.0/729.0);
constexpr float CA61 = (float)(9017.0/3168.0),  CA62 = (float)(-355.0/33.0);
constexpr float CA63 = (float)(46732.0/5247.0), CA64 = (float)(49.0/176.0), CA65 = (float)(-5103.0/18656.0);
constexpr float CB1 = (float)(35.0/384.0), CB3 = (float)(500.0/1113.0), CB4 = (float)(125.0/192.0);
constexpr float CB5 = (float)(-2187.0/6784.0), CB6 = (float)(11.0/84.0);
constexpr float CE1 = (float)(35.0/384.0 - 5179.0/57600.0);
constexpr float CE3 = (float)(500.0/1113.0 - 7571.0/16695.0);
constexpr float CE4 = (float)(125.0/192.0 - 393.0/640.0);
constexpr float CE5 = (float)(-2187.0/6784.0 + 92097.0/339200.0);
constexpr float CE6 = (float)(11.0/84.0 - 187.0/2100.0);
constexpr float CE7 = (float)(-1.0/40.0);

template<int N> struct IC { static constexpr int v = N; };

__device__ __forceinline__ u16 f2bf(float x) {
  u32 u = __builtin_bit_cast(u32, x);
  u32 r = (u + 0x7FFFu + ((u >> 16) & 1u)) >> 16;
  return (u16)r;
}
__device__ __forceinline__ float eluf(float x) {
  return x > 0.f ? x : (__expf(x) - 1.f);
}
// v_cvt_pk_bf16_f32: dst[15:0]=bf16(a), dst[31:16]=bf16(b) (RNE)
__device__ __forceinline__ u32 cvtpk(float a, float b) {
  u32 r; asm("v_cvt_pk_bf16_f32 %0, %1, %2" : "=v"(r) : "v"(a), "v"(b)); return r;
}

// ---------------------------------------------------------------------------
// Prologue
// ---------------------------------------------------------------------------
__global__ void prologue(const float* __restrict__ x0, const float* __restrict__ t,
                         const float* __restrict__ W1, const float* __restrict__ b1,
                         const float* __restrict__ W2, const float* __restrict__ b2,
                         const float* __restrict__ W3, const float* __restrict__ b3,
                         const float* __restrict__ W4, const float* __restrict__ b4,
                         float* __restrict__ ws, float* __restrict__ out)
{
  int gid = blockIdx.x * blockDim.x + threadIdx.x;   // 64*256 = 16384
  out[gid] = x0[gid];
  {
    int k = gid >> 7, j = gid & 127;
    u16* w2th = (u16*)((char*)ws + OFF_W2TH);
    u16* w3th = (u16*)((char*)ws + OFF_W3TH);
    w2th[j*HID + k] = f2bf(W2[gid]);
    w3th[j*HID + k] = f2bf(W3[gid]);
  }
  float* wp = ws + OFF_WPACK/4;
  if (gid < 256) wp[gid] = W1[gid];
  if (gid < 128) {
    wp[256 + gid] = b1[gid];
    wp[384 + gid] = b2[gid];
    wp[512 + gid] = b3[gid];
  }
  if (gid < 2)  wp[640 + gid] = b4[gid];
  if (gid < 256) ((u32*)ws)[gid] = 0u;   // esum64[56] + cnt[56] zeroed
}

// ---------------------------------------------------------------------------
// Persistent solver: 256 WGs x 512 threads, 1 WG/CU (deadlock-proof).
// Single-bf16 weights+activations (r11 numerics: absmax 0.0156, 5x headroom).
// Controller: flat deterministic fixed-point u64 atomic (r10).
// Accept-update is wave-local per row (jc<2 of each row's 16-thread group)
// -> no barrier between update and next phaseA (same-wave DS ordering).
// ---------------------------------------------------------------------------
__global__ __launch_bounds__(NTHR, 2)
void solver(const float* __restrict__ x0, const float* __restrict__ t_arr,
            const float* __restrict__ W4g, float* __restrict__ ws,
            float* __restrict__ out)
{
  const int tid  = threadIdx.x;
  const int wg   = blockIdx.x;
  const int lane = tid & 63;
  const int wv   = tid >> 6;
  const int nl   = lane & 15;      // MFMA fragment index (batch-row within tile)
  const int g    = lane >> 4;      // k-group

  __shared__ __align__(16) u16 Ahi[2][MT][LD];
  __shared__ __align__(16) float Wsm[644];
  __shared__ __align__(16) float kS[7][MT][2];
  __shared__ __align__(16) float yL[MT][2];
  __shared__ __align__(16) float y5L[MT][2];
  __shared__ __align__(16) float pD[8][2][16][2];
  __shared__ u32 bcF;
  __shared__ float bcH;

  // ---- one-time setup ----
  {
    const float* wp = ws + OFF_WPACK/4;
    Wsm[tid] = wp[tid];
    if (tid < 132) Wsm[512 + tid] = wp[512 + tid];
  }
  if (tid < 64) yL[tid >> 1][tid & 1] = x0[wg*64 + tid];

  // resident W2/W3 fragments, single bf16 (A-operand: row n = wv*16+nl)
  const u16* w2th = (const u16*)((const char*)ws + OFF_W2TH);
  const u16* w3th = (const u16*)((const char*)ws + OFF_W3TH);
  short8 W2H[4], W3H[4];
  {
    const int nglob = wv*16 + nl;
#pragma unroll
    for (int ks = 0; ks < 4; ++ks) {
      int off = nglob*HID + ks*32 + g*8;
      W2H[ks] = *(const short8*)(w2th + off);
      W3H[ks] = *(const short8*)(w3th + off);
    }
  }
  // per-lane W4 slice: w4c[r][c] = W4[wv*16+g*4+r][c]
  float w4c[4][2];
#pragma unroll
  for (int r = 0; r < 4; ++r) {
    int n = wv*16 + g*4 + r;
    w4c[r][0] = W4g[n*2 + 0];
    w4c[r][1] = W4g[n*2 + 1];
  }
  __syncthreads();
  const f32x4 bv2 = *(const f32x4*)&Wsm[384 + wv*16 + g*4];
  const f32x4 bv3 = *(const f32x4*)&Wsm[512 + wv*16 + g*4];

  u64* esum = (u64*)((char*)ws + OFF_ESUM);
  u32* cnt  = (u32*)((char*)ws + OFF_CNT);

  float h = 0.5f * (t_arr[1] - t_arr[0]);
  float heff = h;

  // ---- phase A: inline stage combine (from pD) + L1 ----
  auto phaseA = [&](auto SC, int fromPD) {
    constexpr int S = decltype(SC)::v;
    const int m  = tid >> 4;        // 32 rows
    const int jc = tid & 15;        // 16 col-chunks of 8
    float ys0, ys1;
    const float y0 = yL[m][0], y1 = yL[m][1];
    if constexpr (S == 1) {
      ys0 = y0; ys1 = y1;
    } else {
      const int mt = m >> 4, ml = m & 15;
      float kp0, kp1;
      if (S == 2 && !fromPD) {
        kp0 = kS[0][m][0]; kp1 = kS[0][m][1];
      } else {
        kp0 = Wsm[640]; kp1 = Wsm[641];
#pragma unroll
        for (int w = 0; w < 8; ++w) {
          f32x2 p = *(const f32x2*)&pD[w][mt][ml][0];
          kp0 += p[0]; kp1 += p[1];
        }
        if (jc < 2) kS[S-2][m][jc] = jc ? kp1 : kp0;
      }
      if constexpr (S == 2) {
        ys0 = fmaf(heff, CA21*kp0, y0);
        ys1 = fmaf(heff, CA21*kp1, y1);
      } else if constexpr (S == 3) {
        f32x2 k1 = *(const f32x2*)&kS[0][m][0];
        ys0 = fmaf(heff, CA31*k1[0] + CA32*kp0, y0);
        ys1 = fmaf(heff, CA31*k1[1] + CA32*kp1, y1);
      } else if constexpr (S == 4) {
        f32x2 k1 = *(const f32x2*)&kS[0][m][0];
        f32x2 k2 = *(const f32x2*)&kS[1][m][0];
        ys0 = fmaf(heff, CA41*k1[0] + CA42*k2[0] + CA43*kp0, y0);
        ys1 = fmaf(heff, CA41*k1[1] + CA42*k2[1] + CA43*kp1, y1);
      } else if constexpr (S == 5) {
        f32x2 k1 = *(const f32x2*)&kS[0][m][0];
        f32x2 k2 = *(const f32x2*)&kS[1][m][0];
        f32x2 k3 = *(const f32x2*)&kS[2][m][0];
        ys0 = fmaf(heff, CA51*k1[0] + CA52*k2[0] + CA53*k3[0] + CA54*kp0, y0);
        ys1 = fmaf(heff, CA51*k1[1] + CA52*k2[1] + CA53*k3[1] + CA54*kp1, y1);
      } else if constexpr (S == 6) {
        f32x2 k1 = *(const f32x2*)&kS[0][m][0];
        f32x2 k2 = *(const f32x2*)&kS[1][m][0];
        f32x2 k3 = *(const f32x2*)&kS[2][m][0];
        f32x2 k4 = *(const f32x2*)&kS[3][m][0];
        ys0 = fmaf(heff, CA61*k1[0] + CA62*k2[0] + CA63*k3[0] + CA64*k4[0] + CA65*kp0, y0);
        ys1 = fmaf(heff, CA61*k1[1] + CA62*k2[1] + CA63*k3[1] + CA64*k4[1] + CA65*kp1, y1);
      } else {  // S == 7: y5
        f32x2 k1 = *(const f32x2*)&kS[0][m][0];
        f32x2 k3 = *(const f32x2*)&kS[2][m][0];
        f32x2 k4 = *(const f32x2*)&kS[3][m][0];
        f32x2 k5 = *(const f32x2*)&kS[4][m][0];
        ys0 = fmaf(heff, CB1*k1[0] + CB3*k3[0] + CB4*k4[0] + CB5*k5[0] + CB6*kp0, y0);
        ys1 = fmaf(heff, CB1*k1[1] + CB3*k3[1] + CB4*k4[1] + CB5*k5[1] + CB6*kp1, y1);
        if (jc < 2) y5L[m][jc] = jc ? ys1 : ys0;
      }
    }
    // L1: 8 cols per thread, single-bf16 pack
    const int j0 = jc * 8;
    f32x4 w0a = *(const f32x4*)&Wsm[j0],       w0b = *(const f32x4*)&Wsm[j0 + 4];
    f32x4 w1a = *(const f32x4*)&Wsm[128 + j0], w1b = *(const f32x4*)&Wsm[128 + j0 + 4];
    f32x4 ba  = *(const f32x4*)&Wsm[256 + j0], bb  = *(const f32x4*)&Wsm[256 + j0 + 4];
    float v0 = eluf(fmaf(ys1, w1a[0], fmaf(ys0, w0a[0], ba[0])));
    float v1 = eluf(fmaf(ys1, w1a[1], fmaf(ys0, w0a[1], ba[1])));
    float v2 = eluf(fmaf(ys1, w1a[2], fmaf(ys0, w0a[2], ba[2])));
    float v3 = eluf(fmaf(ys1, w1a[3], fmaf(ys0, w0a[3], ba[3])));
    float v4 = eluf(fmaf(ys1, w1b[0], fmaf(ys0, w0b[0], bb[0])));
    float v5 = eluf(fmaf(ys1, w1b[1], fmaf(ys0, w0b[1], bb[1])));
    float v6 = eluf(fmaf(ys1, w1b[2], fmaf(ys0, w0b[2], bb[2])));
    float v7 = eluf(fmaf(ys1, w1b[3], fmaf(ys0, w0b[3], bb[3])));
    u32x4 hp = {cvtpk(v0,v1), cvtpk(v2,v3), cvtpk(v4,v5), cvtpk(v6,v7)};
    *(u32x4*)&Ahi[0][m][j0] = hp;
  };

  // ---- L2: plane0 -> plane1 (8 MFMAs: 2 row-tiles x 4 k-steps) ----
  auto mmL2 = [&]() {
    f32x4 a0[2];
    a0[0] = bv2; a0[1] = bv2;
#pragma unroll
    for (int ks = 0; ks < 4; ++ks)
#pragma unroll
      for (int mt = 0; mt < 2; ++mt) {
        short8 bh = *(const short8*)&Ahi[0][mt*16 + nl][ks*32 + g*8];
        a0[mt] = __builtin_amdgcn_mfma_f32_16x16x32_bf16(W2H[ks], bh, a0[mt], 0, 0, 0);
      }
    const int n0 = wv*16 + g*4;
#pragma unroll
    for (int mt = 0; mt < 2; ++mt) {
      float v0 = eluf(a0[mt][0]);
      float v1 = eluf(a0[mt][1]);
      float v2 = eluf(a0[mt][2]);
      float v3 = eluf(a0[mt][3]);
      u32x2 hp = {cvtpk(v0, v1), cvtpk(v2, v3)};
      *(u32x2*)&Ahi[1][mt*16 + nl][n0] = hp;
    }
  };

  // ---- L3 + fused L4 dot -> pD ----
  auto mmL3 = [&]() {
    f32x4 a0[2];
    a0[0] = bv3; a0[1] = bv3;
#pragma unroll
    for (int ks = 0; ks < 4; ++ks)
#pragma unroll
      for (int mt = 0; mt < 2; ++mt) {
        short8 bh = *(const short8*)&Ahi[1][mt*16 + nl][ks*32 + g*8];
        a0[mt] = __builtin_amdgcn_mfma_f32_16x16x32_bf16(W3H[ks], bh, a0[mt], 0, 0, 0);
      }
#pragma unroll
    for (int mt = 0; mt < 2; ++mt) {
      float v0 = eluf(a0[mt][0]);
      float v1 = eluf(a0[mt][1]);
      float v2 = eluf(a0[mt][2]);
      float v3 = eluf(a0[mt][3]);
      float p0 = v0*w4c[0][0] + v1*w4c[1][0] + v2*w4c[2][0] + v3*w4c[3][0];
      float p1 = v0*w4c[0][1] + v1*w4c[1][1] + v2*w4c[2][1] + v3*w4c[3][1];
      p0 += __shfl_xor(p0, 16); p0 += __shfl_xor(p0, 32);
      p1 += __shfl_xor(p1, 16); p1 += __shfl_xor(p1, 32);
      if (lane < 16) {
        f32x2 pp = {p0, p1};
        *(f32x2*)&pD[wv][mt][lane][0] = pp;
      }
    }
  };

  // ---- main adaptive loop ----
  for (int iv = 0; iv < 7; ++iv) {
    const float t1 = t_arr[iv + 1];
    float tc = t_arr[iv];
    for (int s = 0; s < 8; ++s) {
      const int step = iv*8 + s;
      float rem = t1 - tc;
      if (rem <= 1e-9f) break;          // uniform across all WGs
      heff = fminf(h, rem);

      if (iv == 0 && s == 0) {          // fresh k1 eval
        phaseA(IC<1>{}, 0); __syncthreads();
        mmL2(); __syncthreads();
        mmL3(); __syncthreads();
        phaseA(IC<2>{}, 1);
      } else {
        phaseA(IC<2>{}, 0);             // FSAL: k1 = kS[0]
      }
      __syncthreads(); mmL2(); __syncthreads(); mmL3(); __syncthreads();
      phaseA(IC<3>{}, 1); __syncthreads(); mmL2(); __syncthreads(); mmL3(); __syncthreads();
      phaseA(IC<4>{}, 1); __syncthreads(); mmL2(); __syncthreads(); mmL3(); __syncthreads();
      phaseA(IC<5>{}, 1); __syncthreads(); mmL2(); __syncthreads(); mmL3(); __syncthreads();
      phaseA(IC<6>{}, 1); __syncthreads(); mmL2(); __syncthreads(); mmL3(); __syncthreads();
      phaseA(IC<7>{}, 1); __syncthreads(); mmL2(); __syncthreads(); mmL3(); __syncthreads();
      // pD now holds k7 partials

      // ---- error partial (wave 0) + deterministic fixed-point publish ----
      if (wv == 0) {
        int m = lane >> 1, c = lane & 1;
        int emt = m >> 4, eml = m & 15;
        float kp = Wsm[640 + c];
#pragma unroll
        for (int w = 0; w < 8; ++w) kp += pD[w][emt][eml][c];
        kS[6][m][c] = kp;
        float e = heff * (CE1*kS[0][m][c] + CE3*kS[2][m][c] + CE4*kS[3][m][c]
                        + CE5*kS[4][m][c] + CE6*kS[5][m][c] + CE7*kp);
        float tol = 1e-4f + 1e-3f * fmaxf(fabsf(yL[m][c]), fabsf(y5L[m][c]));
        float rr = e / tol;
        float es = rr * rr;
#pragma unroll
        for (int mk = 1; mk < 64; mk <<= 1) es += __shfl_xor(es, mk);
        if (lane == 0) {
          if (!(es < 1e8f)) es = 1e8f;          // clamp; also catches NaN
          u64 q = (u64)(es * 1048576.0f);       // x 2^20 fixed point
          __hip_atomic_fetch_add(&esum[step], q, __ATOMIC_RELAXED, __HIP_MEMORY_SCOPE_AGENT);
          __hip_atomic_fetch_add(&cnt[step], 1u, __ATOMIC_RELEASE, __HIP_MEMORY_SCOPE_AGENT);
        }
      }
      // ---- every WG: poll + local identical decision ----
      if (tid == 0) {
        while (__hip_atomic_load(&cnt[step], __ATOMIC_ACQUIRE, __HIP_MEMORY_SCOPE_AGENT) < (u32)NWG)
          __builtin_amdgcn_s_sleep(1);
        u64 q = __hip_atomic_load(&esum[step], __ATOMIC_RELAXED, __HIP_MEMORY_SCOPE_AGENT);
        float sum = (float)q * (1.0f/1048576.0f);
        float err_norm = sqrtf(sum * (1.0f/16384.f));
        bool acc = (err_norm <= 1.0f);
        float factor = fminf(10.f, fmaxf(0.2f, 0.9f * powf(fmaxf(err_norm, 1e-10f), -0.2f)));
        bcF = acc ? 1u : 0u;
        bcH = heff * factor;
      }
      __syncthreads();
      // ---- accept-update: wave-local per row (no trailing barrier needed;
      //      next phaseA's readers of yL[m]/kS[0][m] are the same wave) ----
      {
        bool acc = bcF != 0u;
        if (acc) {
          int m = tid >> 4, jc = tid & 15;
          if (jc < 2) {
            yL[m][jc] = y5L[m][jc];
            kS[0][m][jc] = kS[6][m][jc];   // FSAL: k1 <- k7
          }
          tc += heff;
        }
        h = bcH;
      }
    }
    __syncthreads();   // cross-wave: yL updates -> wave0's out write
    if (tid < 64)
      out[(size_t)(iv + 1) * 16384 + wg*64 + tid] = yL[tid >> 1][tid & 1];
  }
}

extern "C" void kernel_launch(void* const* d_in, const int* in_sizes, int n_in,
                              void* d_out, int out_size, void* d_ws, size_t ws_size,
                              hipStream_t stream)
{
  const float* x0 = (const float*)d_in[0];
  const float* t  = (const float*)d_in[1];
  const float* W1 = (const float*)d_in[2];
  const float* b1 = (const float*)d_in[3];
  const float* W2 = (const float*)d_in[4];
  const float* b2 = (const float*)d_in[5];
  const float* W3 = (const float*)d_in[6];
  const float* b3 = (const float*)d_in[7];
  const float* W4 = (const float*)d_in[8];
  const float* b4 = (const float*)d_in[9];
  float* out = (float*)d_out;
  float* ws  = (float*)d_ws;

  prologue<<<64, 256, 0, stream>>>(x0, t, W1, b1, W2, b2, W3, b3, W4, b4, ws, out);
  solver<<<NWG, NTHR, 0, stream>>>(x0, t, W4, ws, out);
}

// Round 13
// 173.323 us; speedup vs baseline: 2.0708x; 1.1476x over previous
//
#include <hip/hip_runtime.h>
#include <stdint.h>

typedef unsigned int u32;
typedef unsigned long long u64;
typedef unsigned short u16;
typedef float f32x4 __attribute__((ext_vector_type(4)));
typedef float f32x2 __attribute__((ext_vector_type(2)));
typedef short short8 __attribute__((ext_vector_type(8)));
typedef unsigned int u32x2 __attribute__((ext_vector_type(2)));
typedef unsigned int u32x4 __attribute__((ext_vector_type(4)));

#define HID  128
#define MT   32        // batch rows per WG
#define NWG  256       // 1 WG/CU -- deadlock-proof envelope (r11 falsified 2 WG/CU)
#define NTHR 512       // 8 waves
#define LD   136       // LDS plane stride in u16 (272B rows)

// ---- ws byte offsets ----
#define OFF_ROOT  0        // 56 roots, 64B stride (fused value<<10 | count)
#define OFF_LEAF  4096     // 56 x 16 leaves, 64B stride
#define OFF_WPACK 61440    // 644 f32: W1(256) b1(128) b2(128) b3(128) b4(2)
#define OFF_W2TH  65536    // 128x128 bf16 [n][k]
#define OFF_W3TH  98304

constexpr float CA21 = (float)(1.0/5.0);
constexpr float CA31 = (float)(3.0/40.0),   CA32 = (float)(9.0/40.0);
constexpr float CA41 = (float)(44.0/45.0),  CA42 = (float)(-56.0/15.0), CA43 = (float)(32.0/9.0);
constexpr float CA51 = (float)(19372.0/6561.0), CA52 = (float)(-25360.0/2187.0);
constexpr float CA53 = (float)(64448.0/6561.0), CA54 = (float)(-212.0/729.0);
constexpr float CA61 = (float)(9017.0/3168.0),  CA62 = (float)(-355.0/33.0);
constexpr float CA63 = (float)(46732.0/5247.0), CA64 = (float)(49.0/176.0), CA65 = (float)(-5103.0/18656.0);
constexpr float CB1 = (float)(35.0/384.0), CB3 = (float)(500.0/1113.0), CB4 = (float)(125.0/192.0);
constexpr float CB5 = (float)(-2187.0/6784.0), CB6 = (float)(11.0/84.0);
constexpr float CE1 = (float)(35.0/384.0 - 5179.0/57600.0);
constexpr float CE3 = (float)(500.0/1113.0 - 7571.0/16695.0);
constexpr float CE4 = (float)(125.0/192.0 - 393.0/640.0);
constexpr float CE5 = (float)(-2187.0/6784.0 + 92097.0/339200.0);
constexpr float CE6 = (float)(11.0/84.0 - 187.0/2100.0);
constexpr float CE7 = (float)(-1.0/40.0);

template<int N> struct IC { static constexpr int v = N; };

__device__ __forceinline__ u16 f2bf(float x) {
  u32 u = __builtin_bit_cast(u32, x);
  u32 r = (u + 0x7FFFu + ((u >> 16) & 1u)) >> 16;
  return (u16)r;
}
__device__ __forceinline__ float eluf(float x) {
  return x > 0.f ? x : (__expf(x) - 1.f);
}
// v_cvt_pk_bf16_f32: dst[15:0]=bf16(a), dst[31:16]=bf16(b) (RNE)
__device__ __forceinline__ u32 cvtpk(float a, float b) {
  u32 r; asm("v_cvt_pk_bf16_f32 %0, %1, %2" : "=v"(r) : "v"(a), "v"(b)); return r;
}

// ---------------------------------------------------------------------------
// Prologue
// ---------------------------------------------------------------------------
__global__ void prologue(const float* __restrict__ x0, const float* __restrict__ t,
                         const float* __restrict__ W1, const float* __restrict__ b1,
                         const float* __restrict__ W2, const float* __restrict__ b2,
                         const float* __restrict__ W3, const float* __restrict__ b3,
                         const float* __restrict__ W4, const float* __restrict__ b4,
                         float* __restrict__ ws, float* __restrict__ out)
{
  int gid = blockIdx.x * blockDim.x + threadIdx.x;   // 64*256 = 16384
  out[gid] = x0[gid];
  {
    int k = gid >> 7, j = gid & 127;
    u16* w2th = (u16*)((char*)ws + OFF_W2TH);
    u16* w3th = (u16*)((char*)ws + OFF_W3TH);
    w2th[j*HID + k] = f2bf(W2[gid]);
    w3th[j*HID + k] = f2bf(W3[gid]);
  }
  float* wp = ws + OFF_WPACK/4;
  if (gid < 256) wp[gid] = W1[gid];
  if (gid < 128) {
    wp[256 + gid] = b1[gid];
    wp[384 + gid] = b2[gid];
    wp[512 + gid] = b3[gid];
  }
  if (gid < 2)  wp[640 + gid] = b4[gid];
  if (gid < 15360) ((u32*)ws)[gid] = 0u;   // roots + leaves zeroed
}

// ---------------------------------------------------------------------------
// Persistent solver: 256 WGs x 512 threads, 1 WG/CU.
// Per-thread register state (y, y5, k1..k6) for its row m = tid>>4.
// Controller: fused (value<<10|count) u64 atomics, 16-leaf tree + root.
// ---------------------------------------------------------------------------
__global__ __launch_bounds__(NTHR, 2)
void solver(const float* __restrict__ x0, const float* __restrict__ t_arr,
            const float* __restrict__ W4g, float* __restrict__ ws,
            float* __restrict__ out)
{
  const int tid  = threadIdx.x;
  const int wg   = blockIdx.x;
  const int lane = tid & 63;
  const int wv   = tid >> 6;
  const int nl   = lane & 15;      // MFMA fragment index
  const int g    = lane >> 4;      // k-group
  const int m    = tid >> 4;       // owned batch row
  const int jc   = tid & 15;       // col-chunk within row

  __shared__ __align__(16) u16 Ahi[2][MT][LD];
  __shared__ __align__(16) float Wsm[644];
  __shared__ __align__(16) float kSm[6][MT][2];   // k1,k3..k6 mirrors for err
  __shared__ __align__(16) float yLm[MT][2];
  __shared__ __align__(16) float y5m[MT][2];
  __shared__ __align__(16) float pD[8][MT][2];
  __shared__ u32 bcF;
  __shared__ float bcH;

  // ---- one-time setup ----
  {
    const float* wp = ws + OFF_WPACK/4;
    Wsm[tid] = wp[tid];
    if (tid < 132) Wsm[512 + tid] = wp[512 + tid];
  }
  float y0r = x0[wg*64 + m*2 + 0];
  float y1r = x0[wg*64 + m*2 + 1];
  if (jc == 0) { yLm[m][0] = y0r; yLm[m][1] = y1r; }

  const u16* w2th = (const u16*)((const char*)ws + OFF_W2TH);
  const u16* w3th = (const u16*)((const char*)ws + OFF_W3TH);
  short8 W2H[4], W3H[4];
  {
    const int nglob = wv*16 + nl;
#pragma unroll
    for (int ks = 0; ks < 4; ++ks) {
      int off = nglob*HID + ks*32 + g*8;
      W2H[ks] = *(const short8*)(w2th + off);
      W3H[ks] = *(const short8*)(w3th + off);
    }
  }
  float w4c[4][2];
#pragma unroll
  for (int r = 0; r < 4; ++r) {
    int n = wv*16 + g*4 + r;
    w4c[r][0] = W4g[n*2 + 0];
    w4c[r][1] = W4g[n*2 + 1];
  }
  __syncthreads();
  const f32x4 bv2 = *(const f32x4*)&Wsm[384 + wv*16 + g*4];
  const f32x4 bv3 = *(const f32x4*)&Wsm[512 + wv*16 + g*4];
  const float b40 = Wsm[640], b41 = Wsm[641];

  float khv[6][2];      // k1..k6, all indices compile-time
  float y5r0 = 0.f, y5r1 = 0.f;

  float h = 0.5f * (t_arr[1] - t_arr[0]);
  float heff = h;

  // ---- phase A: register stage-combine + L1 -> plane0 ----
  auto phaseA = [&](auto SC) {
    constexpr int S = decltype(SC)::v;
    float ys0, ys1;
    if constexpr (S == 1) {
      ys0 = y0r; ys1 = y1r;
    } else {
      float kp0, kp1;
      if constexpr (S == 2) {
        kp0 = khv[0][0]; kp1 = khv[0][1];
      } else {
        kp0 = b40; kp1 = b41;
#pragma unroll
        for (int w = 0; w < 8; ++w) {
          f32x2 p = *(const f32x2*)&pD[w][m][0];
          kp0 += p[0]; kp1 += p[1];
        }
        khv[S-2][0] = kp0; khv[S-2][1] = kp1;
        if constexpr (S >= 4) {          // mirror k3..k6 for the err pass
          if (jc == 0) { kSm[S-2][m][0] = kp0; kSm[S-2][m][1] = kp1; }
        }
      }
      if constexpr (S == 2) {
        ys0 = fmaf(heff, CA21*kp0, y0r);
        ys1 = fmaf(heff, CA21*kp1, y1r);
      } else if constexpr (S == 3) {
        ys0 = fmaf(heff, CA31*khv[0][0] + CA32*kp0, y0r);
        ys1 = fmaf(heff, CA31*khv[0][1] + CA32*kp1, y1r);
      } else if constexpr (S == 4) {
        ys0 = fmaf(heff, CA41*khv[0][0] + CA42*khv[1][0] + CA43*kp0, y0r);
        ys1 = fmaf(heff, CA41*khv[0][1] + CA42*khv[1][1] + CA43*kp1, y1r);
      } else if constexpr (S == 5) {
        ys0 = fmaf(heff, CA51*khv[0][0] + CA52*khv[1][0] + CA53*khv[2][0] + CA54*kp0, y0r);
        ys1 = fmaf(heff, CA51*khv[0][1] + CA52*khv[1][1] + CA53*khv[2][1] + CA54*kp1, y1r);
      } else if constexpr (S == 6) {
        ys0 = fmaf(heff, CA61*khv[0][0] + CA62*khv[1][0] + CA63*khv[2][0] + CA64*khv[3][0] + CA65*kp0, y0r);
        ys1 = fmaf(heff, CA61*khv[0][1] + CA62*khv[1][1] + CA63*khv[2][1] + CA64*khv[3][1] + CA65*kp1, y1r);
      } else {  // S == 7: y5
        ys0 = fmaf(heff, CB1*khv[0][0] + CB3*khv[2][0] + CB4*khv[3][0] + CB5*khv[4][0] + CB6*kp0, y0r);
        ys1 = fmaf(heff, CB1*khv[0][1] + CB3*khv[2][1] + CB4*khv[3][1] + CB5*khv[4][1] + CB6*kp1, y1r);
        y5r0 = ys0; y5r1 = ys1;
        if (jc == 0) { y5m[m][0] = ys0; y5m[m][1] = ys1; }
      }
    }
    // L1: 8 cols per thread, single-bf16 pack -> plane0
    const int j0 = jc * 8;
    f32x4 w0a = *(const f32x4*)&Wsm[j0],       w0b = *(const f32x4*)&Wsm[j0 + 4];
    f32x4 w1a = *(const f32x4*)&Wsm[128 + j0], w1b = *(const f32x4*)&Wsm[128 + j0 + 4];
    f32x4 ba  = *(const f32x4*)&Wsm[256 + j0], bb  = *(const f32x4*)&Wsm[256 + j0 + 4];
    float v0 = eluf(fmaf(ys1, w1a[0], fmaf(ys0, w0a[0], ba[0])));
    float v1 = eluf(fmaf(ys1, w1a[1], fmaf(ys0, w0a[1], ba[1])));
    float v2 = eluf(fmaf(ys1, w1a[2], fmaf(ys0, w0a[2], ba[2])));
    float v3 = eluf(fmaf(ys1, w1a[3], fmaf(ys0, w0a[3], ba[3])));
    float v4 = eluf(fmaf(ys1, w1b[0], fmaf(ys0, w0b[0], bb[0])));
    float v5 = eluf(fmaf(ys1, w1b[1], fmaf(ys0, w0b[1], bb[1])));
    float v6 = eluf(fmaf(ys1, w1b[2], fmaf(ys0, w0b[2], bb[2])));
    float v7 = eluf(fmaf(ys1, w1b[3], fmaf(ys0, w0b[3], bb[3])));
    u32x4 hp = {cvtpk(v0,v1), cvtpk(v2,v3), cvtpk(v4,v5), cvtpk(v6,v7)};
    *(u32x4*)&Ahi[0][m][j0] = hp;
  };

  // ---- L2: plane0 -> plane1 ----
  auto mmL2 = [&]() {
    f32x4 a0[2];
    a0[0] = bv2; a0[1] = bv2;
#pragma unroll
    for (int ks = 0; ks < 4; ++ks)
#pragma unroll
      for (int mt = 0; mt < 2; ++mt) {
        short8 bh = *(const short8*)&Ahi[0][mt*16 + nl][ks*32 + g*8];
        a0[mt] = __builtin_amdgcn_mfma_f32_16x16x32_bf16(W2H[ks], bh, a0[mt], 0, 0, 0);
      }
    const int n0 = wv*16 + g*4;
#pragma unroll
    for (int mt = 0; mt < 2; ++mt) {
      float v0 = eluf(a0[mt][0]);
      float v1 = eluf(a0[mt][1]);
      float v2 = eluf(a0[mt][2]);
      float v3 = eluf(a0[mt][3]);
      u32x2 hp = {cvtpk(v0, v1), cvtpk(v2, v3)};
      *(u32x2*)&Ahi[1][mt*16 + nl][n0] = hp;
    }
  };

  // ---- L3 + fused L4 dot -> pD ----
  auto mmL3 = [&]() {
    f32x4 a0[2];
    a0[0] = bv3; a0[1] = bv3;
#pragma unroll
    for (int ks = 0; ks < 4; ++ks)
#pragma unroll
      for (int mt = 0; mt < 2; ++mt) {
        short8 bh = *(const short8*)&Ahi[1][mt*16 + nl][ks*32 + g*8];
        a0[mt] = __builtin_amdgcn_mfma_f32_16x16x32_bf16(W3H[ks], bh, a0[mt], 0, 0, 0);
      }
#pragma unroll
    for (int mt = 0; mt < 2; ++mt) {
      float v0 = eluf(a0[mt][0]);
      float v1 = eluf(a0[mt][1]);
      float v2 = eluf(a0[mt][2]);
      float v3 = eluf(a0[mt][3]);
      float p0 = v0*w4c[0][0] + v1*w4c[1][0] + v2*w4c[2][0] + v3*w4c[3][0];
      float p1 = v0*w4c[0][1] + v1*w4c[1][1] + v2*w4c[2][1] + v3*w4c[3][1];
      p0 += __shfl_xor(p0, 16); p0 += __shfl_xor(p0, 32);
      p1 += __shfl_xor(p1, 16); p1 += __shfl_xor(p1, 32);
      if (lane < 16) {
        f32x2 pp = {p0, p1};
        *(f32x2*)&pD[wv][mt*16 + lane][0] = pp;
      }
    }
  };

  // ---- main adaptive loop ----
  for (int iv = 0; iv < 7; ++iv) {
    const float t1 = t_arr[iv + 1];
    float tc = t_arr[iv];
    for (int s = 0; s < 8; ++s) {
      const int step = iv*8 + s;
      float rem = t1 - tc;
      if (rem <= 1e-9f) break;          // globally uniform
      heff = fminf(h, rem);

      if (iv == 0 && s == 0) {          // fresh k1 eval
        phaseA(IC<1>{}); __syncthreads();
        mmL2(); __syncthreads();
        mmL3(); __syncthreads();
        float kp0 = b40, kp1 = b41;
#pragma unroll
        for (int w = 0; w < 8; ++w) {
          f32x2 p = *(const f32x2*)&pD[w][m][0];
          kp0 += p[0]; kp1 += p[1];
        }
        khv[0][0] = kp0; khv[0][1] = kp1;
        if (jc == 0) { kSm[0][m][0] = kp0; kSm[0][m][1] = kp1; }
      }
      phaseA(IC<2>{}); __syncthreads(); mmL2(); __syncthreads(); mmL3(); __syncthreads();
      phaseA(IC<3>{}); __syncthreads(); mmL2(); __syncthreads(); mmL3(); __syncthreads();
      phaseA(IC<4>{}); __syncthreads(); mmL2(); __syncthreads(); mmL3(); __syncthreads();
      phaseA(IC<5>{}); __syncthreads(); mmL2(); __syncthreads(); mmL3(); __syncthreads();
      phaseA(IC<6>{}); __syncthreads(); mmL2(); __syncthreads(); mmL3(); __syncthreads();
      phaseA(IC<7>{}); __syncthreads(); mmL2(); __syncthreads(); mmL3(); __syncthreads();
      // pD holds k7 partials

      // ---- error (wave 0) + fused tree publish ----
      if (wv == 0) {
        int em = lane >> 1, ec = lane & 1;
        float kp = ec ? b41 : b40;
#pragma unroll
        for (int w = 0; w < 8; ++w) kp += pD[w][em][ec];
        float e = heff * (CE1*kSm[0][em][ec] + CE3*kSm[2][em][ec] + CE4*kSm[3][em][ec]
                        + CE5*kSm[4][em][ec] + CE6*kSm[5][em][ec] + CE7*kp);
        float tol = 1e-4f + 1e-3f * fmaxf(fabsf(yLm[em][ec]), fabsf(y5m[em][ec]));
        float rr = e / tol;
        float es = rr * rr;
#pragma unroll
        for (int mk = 1; mk < 64; mk <<= 1) es += __shfl_xor(es, mk);
        if (lane == 0) {
          if (!(es < 1e9f)) es = 1e9f;                // clamp + NaN guard
          u64 q = (u64)(es * 1024.0f);                // fixed-point x2^10
          u64 add = (q << 10) | 1ULL;
          u64* leaf = (u64*)((char*)ws + OFF_LEAF + ((size_t)step*16 + (wg & 15))*64);
          u64 old = __hip_atomic_fetch_add(leaf, add, __ATOMIC_ACQ_REL, __HIP_MEMORY_SCOPE_AGENT);
          if ((old & 0x3FFULL) == 15ULL) {            // 16th arrival forwards to root
            u64 tot = old + add;
            u64 radd = ((tot >> 10) << 10) | 1ULL;
            u64* rootp = (u64*)((char*)ws + OFF_ROOT + (size_t)step*64);
            __hip_atomic_fetch_add(rootp, radd, __ATOMIC_ACQ_REL, __HIP_MEMORY_SCOPE_AGENT);
          }
        }
      }
      // all threads: FSAL k7 (overlaps the poll)
      float k7p0 = b40, k7p1 = b41;
#pragma unroll
      for (int w = 0; w < 8; ++w) {
        f32x2 p = *(const f32x2*)&pD[w][m][0];
        k7p0 += p[0]; k7p1 += p[1];
      }
      if (tid == 0) {
        u64* rootp = (u64*)((char*)ws + OFF_ROOT + (size_t)step*64);
        u64 v;
        while (((v = __hip_atomic_load(rootp, __ATOMIC_ACQUIRE, __HIP_MEMORY_SCOPE_AGENT)) & 0x3FFULL) != 16ULL)
          __builtin_amdgcn_s_sleep(1);
        float sum = (float)(v >> 10) * (1.0f/1024.0f);
        float err_norm = sqrtf(sum * (1.0f/16384.f));
        bool acc = (err_norm <= 1.0f);
        float factor = fminf(10.f, fmaxf(0.2f, 0.9f * powf(fmaxf(err_norm, 1e-10f), -0.2f)));
        bcF = acc ? 1u : 0u;
        bcH = heff * factor;
      }
      __syncthreads();
      {
        bool acc = bcF != 0u;
        if (acc) {
          y0r = y5r0; y1r = y5r1;
          khv[0][0] = k7p0; khv[0][1] = k7p1;        // FSAL: k1 <- k7
          if (jc == 0) {
            kSm[0][m][0] = k7p0; kSm[0][m][1] = k7p1;
            yLm[m][0] = y5r0;    yLm[m][1] = y5r1;
          }
          tc += heff;
        }
        h = bcH;
      }
    }
    if (jc == 0) {
      f32x2 yo = {y0r, y1r};
      *(f32x2*)&out[(size_t)(iv + 1) * 16384 + wg*64 + m*2] = yo;
    }
  }
}

extern "C" void kernel_launch(void* const* d_in, const int* in_sizes, int n_in,
                              void* d_out, int out_size, void* d_ws, size_t ws_size,
                              hipStream_t stream)
{
  const float* x0 = (const float*)d_in[0];
  const float* t  = (const float*)d_in[1];
  const float* W1 = (const float*)d_in[2];
  const float* b1 = (const float*)d_in[3];
  const float* W2 = (const float*)d_in[4];
  const float* b2 = (const float*)d_in[5];
  const float* W3 = (const float*)d_in[6];
  const float* b3 = (const float*)d_in[7];
  const float* W4 = (const float*)d_in[8];
  const float* b4 = (const float*)d_in[9];
  float* out = (float*)d_out;
  float* ws  = (float*)d_ws;

  prologue<<<64, 256, 0, stream>>>(x0, t, W1, b1, W2, b2, W3, b3, W4, b4, ws, out);
  solver<<<NWG, NTHR, 0, stream>>>(x0, t, W4, ws, out);
}

// Round 14
// 172.114 us; speedup vs baseline: 2.0853x; 1.0070x over previous
//
#include <hip/hip_runtime.h>
#include <stdint.h>

typedef unsigned int u32;
typedef unsigned long long u64;
typedef unsigned short u16;
typedef float f32x4 __attribute__((ext_vector_type(4)));
typedef float f32x2 __attribute__((ext_vector_type(2)));
typedef short short8 __attribute__((ext_vector_type(8)));
typedef unsigned int u32x2 __attribute__((ext_vector_type(2)));
typedef unsigned int u32x4 __attribute__((ext_vector_type(4)));

#define HID  128
#define MT   32        // batch rows per WG
#define NWG  256       // 1 WG/CU -- deadlock-proof envelope
#define NTHR 256       // 4 waves: half the barrier participants of r13
#define LD   136       // LDS plane stride in u16 (272B rows)

// ---- ws byte offsets (r13 layout) ----
#define OFF_ROOT  0        // 56 roots, 64B stride (fused value<<10 | count)
#define OFF_LEAF  4096     // 56 x 16 leaves, 64B stride
#define OFF_WPACK 61440    // 644 f32: W1(256) b1(128) b2(128) b3(128) b4(2)
#define OFF_W2TH  65536    // 128x128 bf16 [n][k]
#define OFF_W3TH  98304

constexpr float CA21 = (float)(1.0/5.0);
constexpr float CA31 = (float)(3.0/40.0),   CA32 = (float)(9.0/40.0);
constexpr float CA41 = (float)(44.0/45.0),  CA42 = (float)(-56.0/15.0), CA43 = (float)(32.0/9.0);
constexpr float CA51 = (float)(19372.0/6561.0), CA52 = (float)(-25360.0/2187.0);
constexpr float CA53 = (float)(64448.0/6561.0), CA54 = (float)(-212.0/729.0);
constexpr float CA61 = (float)(9017.0/3168.0),  CA62 = (float)(-355.0/33.0);
constexpr float CA63 = (float)(46732.0/5247.0), CA64 = (float)(49.0/176.0), CA65 = (float)(-5103.0/18656.0);
constexpr float CB1 = (float)(35.0/384.0), CB3 = (float)(500.0/1113.0), CB4 = (float)(125.0/192.0);
constexpr float CB5 = (float)(-2187.0/6784.0), CB6 = (float)(11.0/84.0);
constexpr float CE1 = (float)(35.0/384.0 - 5179.0/57600.0);
constexpr float CE3 = (float)(500.0/1113.0 - 7571.0/16695.0);
constexpr float CE4 = (float)(125.0/192.0 - 393.0/640.0);
constexpr float CE5 = (float)(-2187.0/6784.0 + 92097.0/339200.0);
constexpr float CE6 = (float)(11.0/84.0 - 187.0/2100.0);
constexpr float CE7 = (float)(-1.0/40.0);

template<int N> struct IC { static constexpr int v = N; };

__device__ __forceinline__ u16 f2bf(float x) {
  u32 u = __builtin_bit_cast(u32, x);
  u32 r = (u + 0x7FFFu + ((u >> 16) & 1u)) >> 16;
  return (u16)r;
}
__device__ __forceinline__ float eluf(float x) {
  return x > 0.f ? x : (__expf(x) - 1.f);
}
// v_cvt_pk_bf16_f32: dst[15:0]=bf16(a), dst[31:16]=bf16(b) (RNE)
__device__ __forceinline__ u32 cvtpk(float a, float b) {
  u32 r; asm("v_cvt_pk_bf16_f32 %0, %1, %2" : "=v"(r) : "v"(a), "v"(b)); return r;
}

// ---------------------------------------------------------------------------
// Prologue
// ---------------------------------------------------------------------------
__global__ void prologue(const float* __restrict__ x0, const float* __restrict__ t,
                         const float* __restrict__ W1, const float* __restrict__ b1,
                         const float* __restrict__ W2, const float* __restrict__ b2,
                         const float* __restrict__ W3, const float* __restrict__ b3,
                         const float* __restrict__ W4, const float* __restrict__ b4,
                         float* __restrict__ ws, float* __restrict__ out)
{
  int gid = blockIdx.x * blockDim.x + threadIdx.x;   // 64*256 = 16384
  out[gid] = x0[gid];
  {
    int k = gid >> 7, j = gid & 127;
    u16* w2th = (u16*)((char*)ws + OFF_W2TH);
    u16* w3th = (u16*)((char*)ws + OFF_W3TH);
    w2th[j*HID + k] = f2bf(W2[gid]);
    w3th[j*HID + k] = f2bf(W3[gid]);
  }
  float* wp = ws + OFF_WPACK/4;
  if (gid < 256) wp[gid] = W1[gid];
  if (gid < 128) {
    wp[256 + gid] = b1[gid];
    wp[384 + gid] = b2[gid];
    wp[512 + gid] = b3[gid];
  }
  if (gid < 2)  wp[640 + gid] = b4[gid];
  if (gid < 15360) ((u32*)ws)[gid] = 0u;   // roots + leaves zeroed
}

// ---------------------------------------------------------------------------
// Persistent solver: 256 WGs x 256 threads (4 waves), 1 WG/CU.
// Each wave owns 2 n-tiles (32 hidden cols) -> W frags 64 VGPR resident.
// Per-thread register state (y, y5, k1..k6) for its row m = tid>>3.
// Controller: fused u64 atomic tree (r13) + LDS flag spin (no barrier).
// ---------------------------------------------------------------------------
__global__ __launch_bounds__(NTHR, 2)
void solver(const float* __restrict__ x0, const float* __restrict__ t_arr,
            const float* __restrict__ W4g, float* __restrict__ ws,
            float* __restrict__ out)
{
  const int tid  = threadIdx.x;
  const int wg   = blockIdx.x;
  const int lane = tid & 63;
  const int wv   = tid >> 6;       // 4 waves
  const int nl   = lane & 15;      // MFMA fragment index
  const int g    = lane >> 4;      // k-group
  const int m    = tid >> 3;       // owned batch row (32 rows, 8 thr each)
  const int jc   = tid & 7;        // col-chunk within row (16 cols each)

  __shared__ __align__(16) u16 Ahi[2][MT][LD];
  __shared__ __align__(16) float Wsm[644];
  __shared__ __align__(16) float kSm[6][MT][2];   // k mirrors for err pass
  __shared__ __align__(16) float yLm[MT][2];
  __shared__ __align__(16) float y5m[MT][2];
  __shared__ __align__(16) float pD[4][MT][2];
  __shared__ u32 flagL;
  __shared__ u32 bcFl;
  __shared__ float bcHl;

  // ---- one-time setup ----
  {
    const float* wp = ws + OFF_WPACK/4;
    Wsm[tid] = wp[tid];
    Wsm[256 + tid] = wp[256 + tid];
    if (tid < 132) Wsm[512 + tid] = wp[512 + tid];
  }
  if (tid == 0) flagL = 0u;
  float y0r = x0[wg*64 + m*2 + 0];
  float y1r = x0[wg*64 + m*2 + 1];
  if (jc == 0) { yLm[m][0] = y0r; yLm[m][1] = y1r; }

  // resident W2/W3 fragments: 2 n-tiles per wave
  const u16* w2th = (const u16*)((const char*)ws + OFF_W2TH);
  const u16* w3th = (const u16*)((const char*)ws + OFF_W3TH);
  short8 W2H[2][4], W3H[2][4];
#pragma unroll
  for (int nt = 0; nt < 2; ++nt) {
    const int nglob = (wv*2 + nt)*16 + nl;
#pragma unroll
    for (int ks = 0; ks < 4; ++ks) {
      int off = nglob*HID + ks*32 + g*8;
      W2H[nt][ks] = *(const short8*)(w2th + off);
      W3H[nt][ks] = *(const short8*)(w3th + off);
    }
  }
  // per-lane W4 slices: w4c[nt][r][c] = W4[(wv*2+nt)*16+g*4+r][c]
  float w4c[2][4][2];
#pragma unroll
  for (int nt = 0; nt < 2; ++nt)
#pragma unroll
    for (int r = 0; r < 4; ++r) {
      int n = (wv*2 + nt)*16 + g*4 + r;
      w4c[nt][r][0] = W4g[n*2 + 0];
      w4c[nt][r][1] = W4g[n*2 + 1];
    }
  __syncthreads();
  f32x4 bv2[2], bv3[2];
#pragma unroll
  for (int nt = 0; nt < 2; ++nt) {
    bv2[nt] = *(const f32x4*)&Wsm[384 + (wv*2 + nt)*16 + g*4];
    bv3[nt] = *(const f32x4*)&Wsm[512 + (wv*2 + nt)*16 + g*4];
  }
  const float b40 = Wsm[640], b41 = Wsm[641];

  float khv[6][2];      // k1..k6 (all indices compile-time)
  float y5r0 = 0.f, y5r1 = 0.f;

  float h = 0.5f * (t_arr[1] - t_arr[0]);
  float heff = h;

  // ---- phase A: register stage-combine + L1 (16 cols/thread) -> plane0 ----
  auto phaseA = [&](auto SC) {
    constexpr int S = decltype(SC)::v;
    float ys0, ys1;
    if constexpr (S == 1) {
      ys0 = y0r; ys1 = y1r;
    } else {
      float kp0, kp1;
      if constexpr (S == 2) {
        kp0 = khv[0][0]; kp1 = khv[0][1];
      } else {
        kp0 = b40; kp1 = b41;
#pragma unroll
        for (int w = 0; w < 4; ++w) {
          f32x2 p = *(const f32x2*)&pD[w][m][0];
          kp0 += p[0]; kp1 += p[1];
        }
        khv[S-2][0] = kp0; khv[S-2][1] = kp1;
        if constexpr (S >= 4) {
          if (jc == 0) { kSm[S-2][m][0] = kp0; kSm[S-2][m][1] = kp1; }
        }
      }
      if constexpr (S == 2) {
        ys0 = fmaf(heff, CA21*kp0, y0r);
        ys1 = fmaf(heff, CA21*kp1, y1r);
      } else if constexpr (S == 3) {
        ys0 = fmaf(heff, CA31*khv[0][0] + CA32*kp0, y0r);
        ys1 = fmaf(heff, CA31*khv[0][1] + CA32*kp1, y1r);
      } else if constexpr (S == 4) {
        ys0 = fmaf(heff, CA41*khv[0][0] + CA42*khv[1][0] + CA43*kp0, y0r);
        ys1 = fmaf(heff, CA41*khv[0][1] + CA42*khv[1][1] + CA43*kp1, y1r);
      } else if constexpr (S == 5) {
        ys0 = fmaf(heff, CA51*khv[0][0] + CA52*khv[1][0] + CA53*khv[2][0] + CA54*kp0, y0r);
        ys1 = fmaf(heff, CA51*khv[0][1] + CA52*khv[1][1] + CA53*khv[2][1] + CA54*kp1, y1r);
      } else if constexpr (S == 6) {
        ys0 = fmaf(heff, CA61*khv[0][0] + CA62*khv[1][0] + CA63*khv[2][0] + CA64*khv[3][0] + CA65*kp0, y0r);
        ys1 = fmaf(heff, CA61*khv[0][1] + CA62*khv[1][1] + CA63*khv[2][1] + CA64*khv[3][1] + CA65*kp1, y1r);
      } else {  // S == 7: y5
        ys0 = fmaf(heff, CB1*khv[0][0] + CB3*khv[2][0] + CB4*khv[3][0] + CB5*khv[4][0] + CB6*kp0, y0r);
        ys1 = fmaf(heff, CB1*khv[0][1] + CB3*khv[2][1] + CB4*khv[3][1] + CB5*khv[4][1] + CB6*kp1, y1r);
        y5r0 = ys0; y5r1 = ys1;
        if (jc == 0) { y5m[m][0] = ys0; y5m[m][1] = ys1; }
      }
    }
    // L1: 16 cols per thread, single-bf16 pack -> plane0
    const int j0 = jc * 16;
    u32 hp[8];
#pragma unroll
    for (int b = 0; b < 4; ++b) {
      f32x4 w0 = *(const f32x4*)&Wsm[j0 + b*4];
      f32x4 w1 = *(const f32x4*)&Wsm[128 + j0 + b*4];
      f32x4 bb = *(const f32x4*)&Wsm[256 + j0 + b*4];
      float v0 = eluf(fmaf(ys1, w1[0], fmaf(ys0, w0[0], bb[0])));
      float v1 = eluf(fmaf(ys1, w1[1], fmaf(ys0, w0[1], bb[1])));
      float v2 = eluf(fmaf(ys1, w1[2], fmaf(ys0, w0[2], bb[2])));
      float v3 = eluf(fmaf(ys1, w1[3], fmaf(ys0, w0[3], bb[3])));
      hp[b*2 + 0] = cvtpk(v0, v1);
      hp[b*2 + 1] = cvtpk(v2, v3);
    }
    u32x4 pa = {hp[0], hp[1], hp[2], hp[3]};
    u32x4 pb = {hp[4], hp[5], hp[6], hp[7]};
    *(u32x4*)&Ahi[0][m][j0]     = pa;
    *(u32x4*)&Ahi[0][m][j0 + 8] = pb;
  };

  // ---- L2: plane0 -> plane1 (16 MFMAs: 2 mt x 2 nt x 4 ks) ----
  auto mmL2 = [&]() {
    f32x4 acc[2][2];
#pragma unroll
    for (int mt = 0; mt < 2; ++mt)
#pragma unroll
      for (int nt = 0; nt < 2; ++nt) acc[mt][nt] = bv2[nt];
#pragma unroll
    for (int ks = 0; ks < 4; ++ks)
#pragma unroll
      for (int mt = 0; mt < 2; ++mt) {
        short8 bh = *(const short8*)&Ahi[0][mt*16 + nl][ks*32 + g*8];
#pragma unroll
        for (int nt = 0; nt < 2; ++nt)
          acc[mt][nt] = __builtin_amdgcn_mfma_f32_16x16x32_bf16(W2H[nt][ks], bh, acc[mt][nt], 0, 0, 0);
      }
#pragma unroll
    for (int mt = 0; mt < 2; ++mt)
#pragma unroll
      for (int nt = 0; nt < 2; ++nt) {
        float v0 = eluf(acc[mt][nt][0]);
        float v1 = eluf(acc[mt][nt][1]);
        float v2 = eluf(acc[mt][nt][2]);
        float v3 = eluf(acc[mt][nt][3]);
        u32x2 hp = {cvtpk(v0, v1), cvtpk(v2, v3)};
        *(u32x2*)&Ahi[1][mt*16 + nl][(wv*2 + nt)*16 + g*4] = hp;
      }
  };

  // ---- L3 + fused L4 dot -> pD ----
  auto mmL3 = [&]() {
    f32x4 acc[2][2];
#pragma unroll
    for (int mt = 0; mt < 2; ++mt)
#pragma unroll
      for (int nt = 0; nt < 2; ++nt) acc[mt][nt] = bv3[nt];
#pragma unroll
    for (int ks = 0; ks < 4; ++ks)
#pragma unroll
      for (int mt = 0; mt < 2; ++mt) {
        short8 bh = *(const short8*)&Ahi[1][mt*16 + nl][ks*32 + g*8];
#pragma unroll
        for (int nt = 0; nt < 2; ++nt)
          acc[mt][nt] = __builtin_amdgcn_mfma_f32_16x16x32_bf16(W3H[nt][ks], bh, acc[mt][nt], 0, 0, 0);
      }
#pragma unroll
    for (int mt = 0; mt < 2; ++mt) {
      float p0 = 0.f, p1 = 0.f;
#pragma unroll
      for (int nt = 0; nt < 2; ++nt)
#pragma unroll
        for (int r = 0; r < 4; ++r) {
          float v = eluf(acc[mt][nt][r]);
          p0 = fmaf(v, w4c[nt][r][0], p0);
          p1 = fmaf(v, w4c[nt][r][1], p1);
        }
      p0 += __shfl_xor(p0, 16); p0 += __shfl_xor(p0, 32);
      p1 += __shfl_xor(p1, 16); p1 += __shfl_xor(p1, 32);
      if (lane < 16) {
        f32x2 pp = {p0, p1};
        *(f32x2*)&pD[wv][mt*16 + lane][0] = pp;
      }
    }
  };

  // ---- main adaptive loop ----
  for (int iv = 0; iv < 7; ++iv) {
    const float t1 = t_arr[iv + 1];
    float tc = t_arr[iv];
    for (int s = 0; s < 8; ++s) {
      const int step = iv*8 + s;
      float rem = t1 - tc;
      if (rem <= 1e-9f) break;          // globally uniform
      heff = fminf(h, rem);

      if (iv == 0 && s == 0) {          // fresh k1 eval
        phaseA(IC<1>{}); __syncthreads();
        mmL2(); __syncthreads();
        mmL3(); __syncthreads();
        float kp0 = b40, kp1 = b41;
#pragma unroll
        for (int w = 0; w < 4; ++w) {
          f32x2 p = *(const f32x2*)&pD[w][m][0];
          kp0 += p[0]; kp1 += p[1];
        }
        khv[0][0] = kp0; khv[0][1] = kp1;
        if (jc == 0) { kSm[0][m][0] = kp0; kSm[0][m][1] = kp1; }
      }
      phaseA(IC<2>{}); __syncthreads(); mmL2(); __syncthreads(); mmL3(); __syncthreads();
      phaseA(IC<3>{}); __syncthreads(); mmL2(); __syncthreads(); mmL3(); __syncthreads();
      phaseA(IC<4>{}); __syncthreads(); mmL2(); __syncthreads(); mmL3(); __syncthreads();
      phaseA(IC<5>{}); __syncthreads(); mmL2(); __syncthreads(); mmL3(); __syncthreads();
      phaseA(IC<6>{}); __syncthreads(); mmL2(); __syncthreads(); mmL3(); __syncthreads();
      phaseA(IC<7>{}); __syncthreads(); mmL2(); __syncthreads(); mmL3(); __syncthreads();
      // pD holds k7 partials

      // ---- error (wave 0: 64 lanes = 32 rows x 2 dims) + tree publish ----
      if (wv == 0) {
        int em = lane >> 1, ec = lane & 1;
        float kp = ec ? b41 : b40;
#pragma unroll
        for (int w = 0; w < 4; ++w) kp += pD[w][em][ec];
        float e = heff * (CE1*kSm[0][em][ec] + CE3*kSm[2][em][ec] + CE4*kSm[3][em][ec]
                        + CE5*kSm[4][em][ec] + CE6*kSm[5][em][ec] + CE7*kp);
        float tol = 1e-4f + 1e-3f * fmaxf(fabsf(yLm[em][ec]), fabsf(y5m[em][ec]));
        float rr = e / tol;
        float es = rr * rr;
#pragma unroll
        for (int mk = 1; mk < 64; mk <<= 1) es += __shfl_xor(es, mk);
        if (lane == 0) {
          if (!(es < 1e9f)) es = 1e9f;                // clamp + NaN guard
          u64 q = (u64)(es * 1024.0f);                // fixed-point x2^10
          u64 add = (q << 10) | 1ULL;
          u64* leaf = (u64*)((char*)ws + OFF_LEAF + ((size_t)step*16 + (wg & 15))*64);
          u64 old = __hip_atomic_fetch_add(leaf, add, __ATOMIC_ACQ_REL, __HIP_MEMORY_SCOPE_AGENT);
          if ((old & 0x3FFULL) == 15ULL) {            // 16th arrival forwards to root
            u64 tot = old + add;
            u64 radd = ((tot >> 10) << 10) | 1ULL;
            u64* rootp = (u64*)((char*)ws + OFF_ROOT + (size_t)step*64);
            __hip_atomic_fetch_add(rootp, radd, __ATOMIC_ACQ_REL, __HIP_MEMORY_SCOPE_AGENT);
          }
        }
      }
      // all threads: FSAL k7 (overlaps the poll)
      float k7p0 = b40, k7p1 = b41;
#pragma unroll
      for (int w = 0; w < 4; ++w) {
        f32x2 p = *(const f32x2*)&pD[w][m][0];
        k7p0 += p[0]; k7p1 += p[1];
      }
      // tid0 polls global root, publishes via LDS flag (no barrier)
      if (tid == 0) {
        u64* rootp = (u64*)((char*)ws + OFF_ROOT + (size_t)step*64);
        u64 v;
        while (((v = __hip_atomic_load(rootp, __ATOMIC_ACQUIRE, __HIP_MEMORY_SCOPE_AGENT)) & 0x3FFULL) != 16ULL)
          __builtin_amdgcn_s_sleep(1);
        float sum = (float)(v >> 10) * (1.0f/1024.0f);
        float err_norm = sqrtf(sum * (1.0f/16384.f));
        bool acc = (err_norm <= 1.0f);
        float factor = fminf(10.f, fmaxf(0.2f, 0.9f * powf(fmaxf(err_norm, 1e-10f), -0.2f)));
        bcFl = acc ? 1u : 0u;
        bcHl = heff * factor;
        __hip_atomic_store(&flagL, (u32)(step + 1), __ATOMIC_RELEASE, __HIP_MEMORY_SCOPE_WORKGROUP);
      }
      while (__hip_atomic_load(&flagL, __ATOMIC_ACQUIRE, __HIP_MEMORY_SCOPE_WORKGROUP) != (u32)(step + 1))
        __builtin_amdgcn_s_sleep(1);
      {
        bool acc = bcFl != 0u;
        if (acc) {
          y0r = y5r0; y1r = y5r1;
          khv[0][0] = k7p0; khv[0][1] = k7p1;        // FSAL: k1 <- k7
          if (jc == 0) {
            kSm[0][m][0] = k7p0; kSm[0][m][1] = k7p1;
            yLm[m][0] = y5r0;    yLm[m][1] = y5r1;
          }
          tc += heff;
        }
        h = bcHl;
      }
    }
    if (jc == 0) {
      f32x2 yo = {y0r, y1r};
      *(f32x2*)&out[(size_t)(iv + 1) * 16384 + wg*64 + m*2] = yo;
    }
  }
}

extern "C" void kernel_launch(void* const* d_in, const int* in_sizes, int n_in,
                              void* d_out, int out_size, void* d_ws, size_t ws_size,
                              hipStream_t stream)
{
  const float* x0 = (const float*)d_in[0];
  const float* t  = (const float*)d_in[1];
  const float* W1 = (const float*)d_in[2];
  const float* b1 = (const float*)d_in[3];
  const float* W2 = (const float*)d_in[4];
  const float* b2 = (const float*)d_in[5];
  const float* W3 = (const float*)d_in[6];
  const float* b3 = (const float*)d_in[7];
  const float* W4 = (const float*)d_in[8];
  const float* b4 = (const float*)d_in[9];
  float* out = (float*)d_out;
  float* ws  = (float*)d_ws;

  prologue<<<64, 256, 0, stream>>>(x0, t, W1, b1, W2, b2, W3, b3, W4, b4, ws, out);
  solver<<<NWG, NTHR, 0, stream>>>(x0, t, W4, ws, out);
}